// Round 14
// baseline (586.428 us; speedup 1.0000x reference)
//
#include <hip/hip_runtime.h>
#include <hip/hip_bf16.h>

#define B_  4
#define S_  2048
#define D_  1024
#define H_  16
#define DH_ 64
#define M_  (B_*S_)   // 8192

typedef short bf16x8 __attribute__((ext_vector_type(8)));   // 8 bf16 = 4 VGPR
typedef float f32x4  __attribute__((ext_vector_type(4)));
typedef unsigned short u16;

__device__ __forceinline__ u16 f2b(float x) {
    union { __hip_bfloat16 h; u16 u; } c; c.h = __float2bfloat16(x); return c.u;
}

// global -> LDS direct (16B per lane). LDS dst is wave-uniform base + lane*16;
// global src is per-lane (pre-swizzle applied there, rule #21/m173).
__device__ __forceinline__ void gl_lds16(const u16* g, u16* l) {
    __builtin_amdgcn_global_load_lds(
        (const __attribute__((address_space(1))) unsigned int*)g,
        (__attribute__((address_space(3))) unsigned int*)l,
        16, 0, 0);
}

// ---------------- fp32 -> bf16 bulk convert, q/k/v in one launch -------------
__global__ __launch_bounds__(256)
void cvt3(const float* __restrict__ q, const float* __restrict__ k,
          const float* __restrict__ v,
          u16* __restrict__ qb, u16* __restrict__ kb, u16* __restrict__ vb)
{
    const float* src = blockIdx.y == 0 ? q : (blockIdx.y == 1 ? k : v);
    u16*         dst = blockIdx.y == 0 ? qb : (blockIdx.y == 1 ? kb : vb);
    const int i = blockIdx.x*256 + threadIdx.x;      // 0..2^20-1 exact
    float4 a = ((const float4*)src)[2*i];
    float4 b = ((const float4*)src)[2*i+1];
    union { u16 u[8]; uint4 v4; } r;
    r.u[0]=f2b(a.x); r.u[1]=f2b(a.y); r.u[2]=f2b(a.z); r.u[3]=f2b(a.w);
    r.u[4]=f2b(b.x); r.u[5]=f2b(b.y); r.u[6]=f2b(b.z); r.u[7]=f2b(b.w);
    ((uint4*)dst)[i] = r.v4;
}

// ---------------- W[k][n] fp32 -> Wt[n][k] bf16, all four in one launch ------
__global__ __launch_bounds__(256)
void wtrans4(const float* __restrict__ Wq, const float* __restrict__ Wk,
             const float* __restrict__ Wv, const float* __restrict__ Wo,
             u16* __restrict__ Wqt, u16* __restrict__ Wkt,
             u16* __restrict__ Wvt, u16* __restrict__ Wot)
{
    const int z = blockIdx.z;
    const float* W  = z==0 ? Wq  : (z==1 ? Wk  : (z==2 ? Wv  : Wo));
    u16*         Wt = z==0 ? Wqt : (z==1 ? Wkt : (z==2 ? Wvt : Wot));
    __shared__ u16 Ts[64][80];
    const int t = threadIdx.x;
    const int k0 = blockIdx.x*64, n0 = blockIdx.y*64;
    const int kr = t >> 4, nc = (t & 15)*4;
    #pragma unroll
    for (int i = 0; i < 4; ++i) {
        const int kk = kr + i*16;
        float4 wv = *(const float4*)(W + (size_t)(k0 + kk)*D_ + n0 + nc);
        Ts[nc+0][kk] = f2b(wv.x); Ts[nc+1][kk] = f2b(wv.y);
        Ts[nc+2][kk] = f2b(wv.z); Ts[nc+3][kk] = f2b(wv.w);
    }
    __syncthreads();
    const int nr = t >> 2, kc = (t & 3)*16;
    u16* dst = Wt + (size_t)(n0 + nr)*D_ + k0 + kc;
    *(uint4*)(dst)     = *(const uint4*)(&Ts[nr][kc]);
    *(uint4*)(dst + 8) = *(const uint4*)(&Ts[nr][kc + 8]);
}

// ---------------- QKV projection GEMM, one launch (z selects) ----------------
__global__ __launch_bounds__(256)
void proj_qkv(const u16* __restrict__ qb, const u16* __restrict__ kb,
              const u16* __restrict__ vb,
              const u16* __restrict__ Wqt, const u16* __restrict__ Wkt,
              const u16* __restrict__ Wvt,
              const float* __restrict__ bq, const float* __restrict__ bk,
              const float* __restrict__ bv,
              u16* __restrict__ Qhb, u16* __restrict__ Khb,
              u16* __restrict__ Vtb)
{
    const int z = blockIdx.z;
    const u16* Ab     = z==0 ? qb  : (z==1 ? kb  : vb);
    const u16* Wt     = z==0 ? Wqt : (z==1 ? Wkt : Wvt);
    const float* bias = z==0 ? bq  : (z==1 ? bk  : bv);

    const int lin = blockIdx.y*64 + blockIdx.x;      // 0..511
    const int cx = lin & 7, idx = lin >> 3;
    const int nx = cx*8 + (idx & 7), ny = idx >> 3;  // bijective
    const int m0 = nx*128, n0 = ny*128;

    __shared__ u16 AsU[128*64];
    __shared__ u16 BsU[128*64];
    const int t = threadIdx.x;
    const int w = t >> 6, lane = t & 63;
    const int lo = lane & 15, g4 = lane >> 4;
    const int wr = w >> 1, wc = w & 1;
    const int wbase = w*64;

    const f32x4 zero = {0.f, 0.f, 0.f, 0.f};
    f32x4 acc[4][4];
    #pragma unroll
    for (int mi = 0; mi < 4; ++mi)
        #pragma unroll
        for (int ni = 0; ni < 4; ++ni) acc[mi][ni] = zero;

    for (int k0 = 0; k0 < 1024; k0 += 64) {
        __syncthreads();
        #pragma unroll
        for (int c = 0; c < 4; ++c) {
            const int sidx = c*256 + wbase + lane;
            const int row = sidx >> 3;
            const int gblk = (sidx & 7) ^ (row & 7);
            gl_lds16(Ab + (size_t)(m0+row)*D_ + k0 + gblk*8, AsU + (size_t)(c*256 + wbase)*8);
            gl_lds16(Wt + (size_t)(n0+row)*D_ + k0 + gblk*8, BsU + (size_t)(c*256 + wbase)*8);
        }
        __syncthreads();
        #pragma unroll
        for (int ks = 0; ks < 2; ++ks) {
            bf16x8 af[4], bfr[4];
            #pragma unroll
            for (int mi = 0; mi < 4; ++mi) {
                const int row = wr*64 + mi*16 + lo;
                af[mi] = *(const bf16x8*)(AsU + row*64 + (((ks*4+g4) ^ (lo&7))*8));
            }
            #pragma unroll
            for (int ni = 0; ni < 4; ++ni) {
                const int row = wc*64 + ni*16 + lo;
                bfr[ni] = *(const bf16x8*)(BsU + row*64 + (((ks*4+g4) ^ (lo&7))*8));
            }
            #pragma unroll
            for (int mi = 0; mi < 4; ++mi)
                #pragma unroll
                for (int ni = 0; ni < 4; ++ni)
                    acc[mi][ni] = __builtin_amdgcn_mfma_f32_16x16x32_bf16(
                        af[mi], bfr[ni], acc[mi][ni], 0, 0, 0);
        }
    }

    if (z < 2) {
        u16* C = z==0 ? Qhb : Khb;
        #pragma unroll
        for (int ni = 0; ni < 4; ++ni) {
            const int n = n0 + wc*64 + ni*16 + lo;
            const float bb = bias[n];
            #pragma unroll
            for (int mi = 0; mi < 4; ++mi)
                #pragma unroll
                for (int j = 0; j < 4; ++j) {
                    const size_t m = (size_t)(m0 + wr*64 + mi*16 + g4*4 + j);
                    C[m*D_ + n] = f2b(acc[mi][ni][j] + bb);
                }
        }
    } else {
        // transposed: Vt[b*D_ + n][s], s = within-batch row
        const int bb_ = m0 >> 11;
        const int sbase = (m0 & 2047) + wr*64;
        #pragma unroll
        for (int ni = 0; ni < 4; ++ni) {
            const int n = n0 + wc*64 + ni*16 + lo;
            const float bv_ = bias[n];
            u16* vrow = Vtb + (size_t)(bb_*D_ + n)*S_ + sbase;
            #pragma unroll
            for (int mi = 0; mi < 4; ++mi) {
                union { u16 u[4]; uint2 v2; } pk;
                #pragma unroll
                for (int j = 0; j < 4; ++j) pk.u[j] = f2b(acc[mi][ni][j] + bv_);
                *(uint2*)(vrow + mi*16 + g4*4) = pk.v2;  // 8B, aligned
            }
        }
    }
}

// ---------------- fused attention v4 (round 14) ------------------------------
// loop1: rowsums (K via LDS). loop2: QK^T recompute; exp cluster writes P to
// LDS ONLY (no global stores, no 64-bit addr math); PV cluster piggybacks the
// attn store on the EXISTING pa ds_read: unpack bf16x8 -> 8 fp32 (<<16),
// * row-inv, 2x f32x4 nt-stores (8 wide stores/kt, was 32 scalar dwords).
// Row-inv for row qs*16+lo obtained via one-time per-wave LDS bounce.
__global__ __launch_bounds__(256)
void attn_fused4(const u16* __restrict__ Qh, const u16* __restrict__ Kh,
                 const u16* __restrict__ Vt,
                 u16* __restrict__ ctxb, float* __restrict__ attn)
{
    __shared__ u16 Kbuf[64*64];     // 8KB, chunk-swizzled
    __shared__ u16 Vbuf[64*64];     // 8KB
    __shared__ u16 Plds[4*2048];    // per-wave 32q x 64key, XOR-swizzled
    __shared__ float Rinv[4][32];   // per-wave row inverses
    const int t = threadIdx.x, w = t >> 6, lane = t & 63;
    const int lo = lane & 15, g4 = lane >> 4;
    const int wbase = w*64;

    const int lin = (blockIdx.z*16 + blockIdx.y)*16 + blockIdx.x;  // 0..1023
    const int cx = lin & 7, idx = lin >> 3;
    const int nl = cx*128 + idx;                  // bijective chunked
    const int qb_ = nl & 15, bh = nl >> 4;
    const int h = bh & 15, b = bh >> 4;
    const int qbase = qb_*128 + w*32;
    u16* Pw = Plds + w*2048;

    bf16x8 qf[2][2];
    #pragma unroll
    for (int qs = 0; qs < 2; ++qs)
        #pragma unroll
        for (int ks = 0; ks < 2; ++ks)
            qf[qs][ks] = *(const bf16x8*)(Qh + (size_t)(b*S_ + qbase + qs*16 + lo)*D_ + h*DH_ + ks*32 + g4*8);

    const f32x4 zero = {0.f, 0.f, 0.f, 0.f};

    // ---------------- loop1: rowsums only (K via LDS) ----------------
    float rs[2][4] = {};
    for (int kt = 0; kt < 32; ++kt) {
        __syncthreads();   // prev iter's Kbuf readers done
        #pragma unroll
        for (int c = 0; c < 2; ++c) {
            const int sidx = c*256 + wbase + lane;       // 0..511
            const int row = sidx >> 3;                   // 0..63
            const int gblk = (sidx & 7) ^ (row & 7);
            gl_lds16(Kh + (size_t)(b*S_ + kt*64 + row)*D_ + h*DH_ + gblk*8,
                     Kbuf + (size_t)(c*256 + wbase)*8);
        }
        __syncthreads();   // staging complete
        f32x4 sacc[2][4];
        #pragma unroll
        for (int qs = 0; qs < 2; ++qs)
            #pragma unroll
            for (int ni = 0; ni < 4; ++ni) sacc[qs][ni] = zero;
        __builtin_amdgcn_s_setprio(1);
        #pragma unroll
        for (int ks = 0; ks < 2; ++ks)
            #pragma unroll
            for (int ni = 0; ni < 4; ++ni) {
                const int row = ni*16 + lo;
                const bf16x8 kf = *(const bf16x8*)(Kbuf + row*64 + (((ks*4+g4) ^ (lo&7))*8));
                sacc[0][ni] = __builtin_amdgcn_mfma_f32_16x16x32_bf16(qf[0][ks], kf, sacc[0][ni], 0, 0, 0);
                sacc[1][ni] = __builtin_amdgcn_mfma_f32_16x16x32_bf16(qf[1][ks], kf, sacc[1][ni], 0, 0, 0);
            }
        __builtin_amdgcn_s_setprio(0);
        #pragma unroll
        for (int qs = 0; qs < 2; ++qs)
            #pragma unroll
            for (int ni = 0; ni < 4; ++ni)
                #pragma unroll
                for (int j = 0; j < 4; ++j)
                    rs[qs][j] += __expf(sacc[qs][ni][j] * 0.125f);
    }

    float invp[2][4];
    #pragma unroll
    for (int qs = 0; qs < 2; ++qs)
        #pragma unroll
        for (int j = 0; j < 4; ++j) {
            float r = rs[qs][j];
            r += __shfl_xor(r, 1); r += __shfl_xor(r, 2);
            r += __shfl_xor(r, 4); r += __shfl_xor(r, 8);
            invp[qs][j] = 1.0f / r;
        }
    // publish row-inverses; re-read indexed by lo (store rows are qs*16+lo)
    if (lo == 0) {
        #pragma unroll
        for (int qs = 0; qs < 2; ++qs)
            #pragma unroll
            for (int j = 0; j < 4; ++j)
                Rinv[w][qs*16 + g4*4 + j] = invp[qs][j];
    }
    __syncthreads();
    const float invq[2] = { Rinv[w][lo], Rinv[w][16 + lo] };

    // ---------------- loop2: recompute + P->LDS + PV + piggyback store -------
    // attn row base for this lane's STORE rows: q = qbase + qs*16 + lo
    float* arow0 = attn + ((size_t)(b*H_ + h)*S_ + qbase + lo)*S_;
    float* arow1 = arow0 + (size_t)16*S_;

    f32x4 cacc[2][4];
    #pragma unroll
    for (int qs = 0; qs < 2; ++qs)
        #pragma unroll
        for (int ni = 0; ni < 4; ++ni) cacc[qs][ni] = zero;

    for (int kt = 0; kt < 32; ++kt) {
        __syncthreads();   // prev readers done
        #pragma unroll
        for (int c = 0; c < 2; ++c) {
            const int sidx = c*256 + wbase + lane;
            const int row = sidx >> 3;
            const int gblk = (sidx & 7) ^ (row & 7);
            gl_lds16(Kh + (size_t)(b*S_ + kt*64 + row)*D_ + h*DH_ + gblk*8,
                     Kbuf + (size_t)(c*256 + wbase)*8);
            gl_lds16(Vt + (size_t)(b*D_ + h*DH_ + row)*S_ + kt*64 + gblk*8,
                     Vbuf + (size_t)(c*256 + wbase)*8);
        }
        __syncthreads();   // staging complete
        f32x4 sacc[2][4];
        #pragma unroll
        for (int qs = 0; qs < 2; ++qs)
            #pragma unroll
            for (int ni = 0; ni < 4; ++ni) sacc[qs][ni] = zero;
        __builtin_amdgcn_s_setprio(1);
        #pragma unroll
        for (int ks = 0; ks < 2; ++ks)
            #pragma unroll
            for (int ni = 0; ni < 4; ++ni) {
                const int row = ni*16 + lo;
                const bf16x8 kf = *(const bf16x8*)(Kbuf + row*64 + (((ks*4+g4) ^ (lo&7))*8));
                sacc[0][ni] = __builtin_amdgcn_mfma_f32_16x16x32_bf16(qf[0][ks], kf, sacc[0][ni], 0, 0, 0);
                sacc[1][ni] = __builtin_amdgcn_mfma_f32_16x16x32_bf16(qf[1][ks], kf, sacc[1][ni], 0, 0, 0);
            }
        __builtin_amdgcn_s_setprio(0);
        // exp -> P LDS only (unnormalized bf16)
        #pragma unroll
        for (int qs = 0; qs < 2; ++qs)
            #pragma unroll
            for (int ni = 0; ni < 4; ++ni)
                #pragma unroll
                for (int j = 0; j < 4; ++j) {
                    const float p = __expf(sacc[qs][ni][j] * 0.125f);
                    const int row = qs*16 + g4*4 + j, key = ni*16 + lo;
                    Pw[row*64 + (((key >> 3) ^ (row & 7))*8) + (key & 7)] = f2b(p);
                }
        __builtin_amdgcn_s_setprio(1);
        #pragma unroll
        for (int ks = 0; ks < 2; ++ks) {
            bf16x8 vf[4];
            #pragma unroll
            for (int ni = 0; ni < 4; ++ni) {
                const int row = ni*16 + lo;
                vf[ni] = *(const bf16x8*)(Vbuf + row*64 + (((ks*4+g4) ^ (lo&7))*8));
            }
            #pragma unroll
            for (int qs = 0; qs < 2; ++qs) {
                const int prow = qs*16 + lo;
                const bf16x8 pa = *(const bf16x8*)(Pw + prow*64 + (((ks*4 + g4) ^ (lo & 7))*8));
                // piggyback attn store: pa = keys [ks*32+g4*8, +8) of row prow
                union { bf16x8 v; u16 u[8]; } pu; pu.v = pa;
                f32x4 s0, s1;
                #pragma unroll
                for (int e = 0; e < 4; ++e) {
                    s0[e] = __uint_as_float((unsigned)pu.u[e]     << 16) * invq[qs];
                    s1[e] = __uint_as_float((unsigned)pu.u[e + 4] << 16) * invq[qs];
                }
                float* ar = (qs ? arow1 : arow0) + kt*64 + ks*32 + g4*8;
                __builtin_nontemporal_store(s0, (f32x4*)(ar));
                __builtin_nontemporal_store(s1, (f32x4*)(ar + 4));
                #pragma unroll
                for (int ni = 0; ni < 4; ++ni)
                    cacc[qs][ni] = __builtin_amdgcn_mfma_f32_16x16x32_bf16(pa, vf[ni], cacc[qs][ni], 0, 0, 0);
            }
        }
        __builtin_amdgcn_s_setprio(0);
    }

    #pragma unroll
    for (int qs = 0; qs < 2; ++qs)
        #pragma unroll
        for (int j = 0; j < 4; ++j) {
            const float inv = invp[qs][j];
            #pragma unroll
            for (int ni = 0; ni < 4; ++ni)
                ctxb[(size_t)(b*S_ + qbase + qs*16 + g4*4 + j)*D_ + h*DH_ + ni*16 + lo] =
                    f2b(cacc[qs][ni][j] * inv);
        }
}

// ---------------- output GEMM: out[M][1024] = ctx@Wo + bo (fp32 out) ---------
__global__ __launch_bounds__(256)
void gemm_out(const u16* __restrict__ Ab, const u16* __restrict__ Wt,
              const float* __restrict__ bias, float* __restrict__ Cf)
{
    const int lin = blockIdx.y*64 + blockIdx.x;
    const int cx = lin & 7, idx = lin >> 3;
    const int nx = cx*8 + (idx & 7), ny = idx >> 3;
    const int m0 = nx*128, n0 = ny*128;

    __shared__ u16 AsU[128*64];
    __shared__ u16 BsU[128*64];
    const int t = threadIdx.x;
    const int w = t >> 6, lane = t & 63;
    const int lo = lane & 15, g4 = lane >> 4;
    const int wr = w >> 1, wc = w & 1;
    const int wbase = w*64;

    const f32x4 zero = {0.f, 0.f, 0.f, 0.f};
    f32x4 acc[4][4];
    #pragma unroll
    for (int mi = 0; mi < 4; ++mi)
        #pragma unroll
        for (int ni = 0; ni < 4; ++ni) acc[mi][ni] = zero;

    for (int k0 = 0; k0 < 1024; k0 += 64) {
        __syncthreads();
        #pragma unroll
        for (int c = 0; c < 4; ++c) {
            const int sidx = c*256 + wbase + lane;
            const int row = sidx >> 3;
            const int gblk = (sidx & 7) ^ (row & 7);
            gl_lds16(Ab + (size_t)(m0+row)*D_ + k0 + gblk*8, AsU + (size_t)(c*256 + wbase)*8);
            gl_lds16(Wt + (size_t)(n0+row)*D_ + k0 + gblk*8, BsU + (size_t)(c*256 + wbase)*8);
        }
        __syncthreads();
        #pragma unroll
        for (int ks = 0; ks < 2; ++ks) {
            bf16x8 af[4], bfr[4];
            #pragma unroll
            for (int mi = 0; mi < 4; ++mi) {
                const int row = wr*64 + mi*16 + lo;
                af[mi] = *(const bf16x8*)(AsU + row*64 + (((ks*4+g4) ^ (lo&7))*8));
            }
            #pragma unroll
            for (int ni = 0; ni < 4; ++ni) {
                const int row = wc*64 + ni*16 + lo;
                bfr[ni] = *(const bf16x8*)(BsU + row*64 + (((ks*4+g4) ^ (lo&7))*8));
            }
            #pragma unroll
            for (int mi = 0; mi < 4; ++mi)
                #pragma unroll
                for (int ni = 0; ni < 4; ++ni)
                    acc[mi][ni] = __builtin_amdgcn_mfma_f32_16x16x32_bf16(
                        af[mi], bfr[ni], acc[mi][ni], 0, 0, 0);
        }
    }

    #pragma unroll
    for (int ni = 0; ni < 4; ++ni) {
        const int n = n0 + wc*64 + ni*16 + lo;
        const float bb = bias[n];
        #pragma unroll
        for (int mi = 0; mi < 4; ++mi)
            #pragma unroll
            for (int j = 0; j < 4; ++j) {
                const size_t m = (size_t)(m0 + wr*64 + mi*16 + g4*4 + j);
                Cf[m*D_ + n] = acc[mi][ni][j] + bb;
            }
    }
}

// ----------------------------------------------------------------------------
extern "C" void kernel_launch(void* const* d_in, const int* in_sizes, int n_in,
                              void* d_out, int out_size, void* d_ws, size_t ws_size,
                              hipStream_t stream)
{
    (void)in_sizes; (void)n_in; (void)out_size; (void)ws_size;
    const float* v  = (const float*)d_in[0];
    const float* k  = (const float*)d_in[1];
    const float* q  = (const float*)d_in[2];
    const float* Wq = (const float*)d_in[3];
    const float* bq = (const float*)d_in[4];
    const float* Wk = (const float*)d_in[5];
    const float* bk = (const float*)d_in[6];
    const float* Wv = (const float*)d_in[7];
    const float* bv = (const float*)d_in[8];
    const float* Wo = (const float*)d_in[9];
    const float* bo = (const float*)d_in[10];

    float* out  = (float*)d_out;                  // (B,S,D) fp32
    float* attn = out + (size_t)M_*D_;            // (B,H,S,S) fp32

    u16* qb  = (u16*)d_ws;
    u16* kb  = qb  + (size_t)M_*D_;
    u16* vb  = kb  + (size_t)M_*D_;
    u16* Wqt = vb  + (size_t)M_*D_;
    u16* Wkt = Wqt + (size_t)D_*D_;
    u16* Wvt = Wkt + (size_t)D_*D_;
    u16* Wot = Wvt + (size_t)D_*D_;
    u16* Qhb = Wot + (size_t)D_*D_;
    u16* Khb = Qhb + (size_t)M_*D_;
    u16* Vtb = Khb + (size_t)M_*D_;
    u16* ctxb = qb;                               // reuse (dead after q-proj)

    dim3 b256(256);

    cvt3       <<<dim3(4096, 3),   b256, 0, stream>>>(q, k, v, qb, kb, vb);
    wtrans4    <<<dim3(16, 16, 4), b256, 0, stream>>>(Wq, Wk, Wv, Wo, Wqt, Wkt, Wvt, Wot);
    proj_qkv   <<<dim3(64, 8, 3),  b256, 0, stream>>>(qb, kb, vb, Wqt, Wkt, Wvt,
                                                      bq, bk, bv, Qhb, Khb, Vtb);
    attn_fused4<<<dim3(16, 16, 4), b256, 0, stream>>>(Qhb, Khb, Vtb, ctxb, attn);
    gemm_out   <<<dim3(64, 8),     b256, 0, stream>>>(ctxb, Wot, bo, out);
}

// Round 15
// 515.020 us; speedup vs baseline: 1.1387x; 1.1387x over previous
//
#include <hip/hip_runtime.h>
#include <hip/hip_bf16.h>

#define B_  4
#define S_  2048
#define D_  1024
#define H_  16
#define DH_ 64
#define M_  (B_*S_)   // 8192

typedef short bf16x8 __attribute__((ext_vector_type(8)));   // 8 bf16 = 4 VGPR
typedef float f32x4  __attribute__((ext_vector_type(4)));
typedef unsigned short u16;

__device__ __forceinline__ u16 f2b(float x) {
    union { __hip_bfloat16 h; u16 u; } c; c.h = __float2bfloat16(x); return c.u;
}

// global -> LDS direct (16B per lane). LDS dst is wave-uniform base + lane*16;
// global src is per-lane (pre-swizzle applied there, rule #21/m173).
__device__ __forceinline__ void gl_lds16(const u16* g, u16* l) {
    __builtin_amdgcn_global_load_lds(
        (const __attribute__((address_space(1))) unsigned int*)g,
        (__attribute__((address_space(3))) unsigned int*)l,
        16, 0, 0);
}

// ---------------- fp32 -> bf16 bulk convert, q/k/v in one launch -------------
__global__ __launch_bounds__(256)
void cvt3(const float* __restrict__ q, const float* __restrict__ k,
          const float* __restrict__ v,
          u16* __restrict__ qb, u16* __restrict__ kb, u16* __restrict__ vb)
{
    const float* src = blockIdx.y == 0 ? q : (blockIdx.y == 1 ? k : v);
    u16*         dst = blockIdx.y == 0 ? qb : (blockIdx.y == 1 ? kb : vb);
    const int i = blockIdx.x*256 + threadIdx.x;      // 0..2^20-1 exact
    float4 a = ((const float4*)src)[2*i];
    float4 b = ((const float4*)src)[2*i+1];
    union { u16 u[8]; uint4 v4; } r;
    r.u[0]=f2b(a.x); r.u[1]=f2b(a.y); r.u[2]=f2b(a.z); r.u[3]=f2b(a.w);
    r.u[4]=f2b(b.x); r.u[5]=f2b(b.y); r.u[6]=f2b(b.z); r.u[7]=f2b(b.w);
    ((uint4*)dst)[i] = r.v4;
}

// ---------------- W[k][n] fp32 -> Wt[n][k] bf16, all four in one launch ------
__global__ __launch_bounds__(256)
void wtrans4(const float* __restrict__ Wq, const float* __restrict__ Wk,
             const float* __restrict__ Wv, const float* __restrict__ Wo,
             u16* __restrict__ Wqt, u16* __restrict__ Wkt,
             u16* __restrict__ Wvt, u16* __restrict__ Wot)
{
    const int z = blockIdx.z;
    const float* W  = z==0 ? Wq  : (z==1 ? Wk  : (z==2 ? Wv  : Wo));
    u16*         Wt = z==0 ? Wqt : (z==1 ? Wkt : (z==2 ? Wvt : Wot));
    __shared__ u16 Ts[64][80];
    const int t = threadIdx.x;
    const int k0 = blockIdx.x*64, n0 = blockIdx.y*64;
    const int kr = t >> 4, nc = (t & 15)*4;
    #pragma unroll
    for (int i = 0; i < 4; ++i) {
        const int kk = kr + i*16;
        float4 wv = *(const float4*)(W + (size_t)(k0 + kk)*D_ + n0 + nc);
        Ts[nc+0][kk] = f2b(wv.x); Ts[nc+1][kk] = f2b(wv.y);
        Ts[nc+2][kk] = f2b(wv.z); Ts[nc+3][kk] = f2b(wv.w);
    }
    __syncthreads();
    const int nr = t >> 2, kc = (t & 3)*16;
    u16* dst = Wt + (size_t)(n0 + nr)*D_ + k0 + kc;
    *(uint4*)(dst)     = *(const uint4*)(&Ts[nr][kc]);
    *(uint4*)(dst + 8) = *(const uint4*)(&Ts[nr][kc + 8]);
}

// ---------------- QKV projection GEMM, one launch (z selects) ----------------
__global__ __launch_bounds__(256)
void proj_qkv(const u16* __restrict__ qb, const u16* __restrict__ kb,
              const u16* __restrict__ vb,
              const u16* __restrict__ Wqt, const u16* __restrict__ Wkt,
              const u16* __restrict__ Wvt,
              const float* __restrict__ bq, const float* __restrict__ bk,
              const float* __restrict__ bv,
              u16* __restrict__ Qhb, u16* __restrict__ Khb,
              u16* __restrict__ Vtb)
{
    const int z = blockIdx.z;
    const u16* Ab     = z==0 ? qb  : (z==1 ? kb  : vb);
    const u16* Wt     = z==0 ? Wqt : (z==1 ? Wkt : Wvt);
    const float* bias = z==0 ? bq  : (z==1 ? bk  : bv);

    const int lin = blockIdx.y*64 + blockIdx.x;      // 0..511
    const int cx = lin & 7, idx = lin >> 3;
    const int nx = cx*8 + (idx & 7), ny = idx >> 3;  // bijective
    const int m0 = nx*128, n0 = ny*128;

    __shared__ u16 AsU[128*64];
    __shared__ u16 BsU[128*64];
    const int t = threadIdx.x;
    const int w = t >> 6, lane = t & 63;
    const int lo = lane & 15, g4 = lane >> 4;
    const int wr = w >> 1, wc = w & 1;
    const int wbase = w*64;

    const f32x4 zero = {0.f, 0.f, 0.f, 0.f};
    f32x4 acc[4][4];
    #pragma unroll
    for (int mi = 0; mi < 4; ++mi)
        #pragma unroll
        for (int ni = 0; ni < 4; ++ni) acc[mi][ni] = zero;

    for (int k0 = 0; k0 < 1024; k0 += 64) {
        __syncthreads();
        #pragma unroll
        for (int c = 0; c < 4; ++c) {
            const int sidx = c*256 + wbase + lane;
            const int row = sidx >> 3;
            const int gblk = (sidx & 7) ^ (row & 7);
            gl_lds16(Ab + (size_t)(m0+row)*D_ + k0 + gblk*8, AsU + (size_t)(c*256 + wbase)*8);
            gl_lds16(Wt + (size_t)(n0+row)*D_ + k0 + gblk*8, BsU + (size_t)(c*256 + wbase)*8);
        }
        __syncthreads();
        #pragma unroll
        for (int ks = 0; ks < 2; ++ks) {
            bf16x8 af[4], bfr[4];
            #pragma unroll
            for (int mi = 0; mi < 4; ++mi) {
                const int row = wr*64 + mi*16 + lo;
                af[mi] = *(const bf16x8*)(AsU + row*64 + (((ks*4+g4) ^ (lo&7))*8));
            }
            #pragma unroll
            for (int ni = 0; ni < 4; ++ni) {
                const int row = wc*64 + ni*16 + lo;
                bfr[ni] = *(const bf16x8*)(BsU + row*64 + (((ks*4+g4) ^ (lo&7))*8));
            }
            #pragma unroll
            for (int mi = 0; mi < 4; ++mi)
                #pragma unroll
                for (int ni = 0; ni < 4; ++ni)
                    acc[mi][ni] = __builtin_amdgcn_mfma_f32_16x16x32_bf16(
                        af[mi], bfr[ni], acc[mi][ni], 0, 0, 0);
        }
    }

    if (z < 2) {
        u16* C = z==0 ? Qhb : Khb;
        #pragma unroll
        for (int ni = 0; ni < 4; ++ni) {
            const int n = n0 + wc*64 + ni*16 + lo;
            const float bb = bias[n];
            #pragma unroll
            for (int mi = 0; mi < 4; ++mi)
                #pragma unroll
                for (int j = 0; j < 4; ++j) {
                    const size_t m = (size_t)(m0 + wr*64 + mi*16 + g4*4 + j);
                    C[m*D_ + n] = f2b(acc[mi][ni][j] + bb);
                }
        }
    } else {
        // transposed: Vt[b*D_ + n][s], s = within-batch row
        const int bb_ = m0 >> 11;
        const int sbase = (m0 & 2047) + wr*64;
        #pragma unroll
        for (int ni = 0; ni < 4; ++ni) {
            const int n = n0 + wc*64 + ni*16 + lo;
            const float bv_ = bias[n];
            u16* vrow = Vtb + (size_t)(bb_*D_ + n)*S_ + sbase;
            #pragma unroll
            for (int mi = 0; mi < 4; ++mi) {
                union { u16 u[4]; uint2 v2; } pk;
                #pragma unroll
                for (int j = 0; j < 4; ++j) pk.u[j] = f2b(acc[mi][ni][j] + bv_);
                *(uint2*)(vrow + mi*16 + g4*4) = pk.v2;  // 8B, aligned
            }
        }
    }
}

// ---------------- fused attention v5 (round 15) ------------------------------
// loop1: rowsums with DIRECT global K reads (no LDS, no barriers) -> deletes
// 32 barrier pairs and lets waves skew before entering loop2. K is L2-hot.
// loop2: r13 verbatim (best measured): K,V staged via global_load_lds once
// per block per kt; exp cluster does P->LDS + scalar nt-store normalized attn.
__global__ __launch_bounds__(256)
void attn_fused5(const u16* __restrict__ Qh, const u16* __restrict__ Kh,
                 const u16* __restrict__ Vt,
                 u16* __restrict__ ctxb, float* __restrict__ attn)
{
    __shared__ u16 Kbuf[64*64];     // 8KB, chunk-swizzled
    __shared__ u16 Vbuf[64*64];     // 8KB
    __shared__ u16 Plds[4*2048];    // per-wave 32q x 64key, XOR-swizzled
    const int t = threadIdx.x, w = t >> 6, lane = t & 63;
    const int lo = lane & 15, g4 = lane >> 4;
    const int wbase = w*64;

    const int lin = (blockIdx.z*16 + blockIdx.y)*16 + blockIdx.x;  // 0..1023
    const int cx = lin & 7, idx = lin >> 3;
    const int nl = cx*128 + idx;                  // bijective chunked
    const int qb_ = nl & 15, bh = nl >> 4;
    const int h = bh & 15, b = bh >> 4;
    const int qbase = qb_*128 + w*32;
    u16* Pw = Plds + w*2048;

    bf16x8 qf[2][2];
    #pragma unroll
    for (int qs = 0; qs < 2; ++qs)
        #pragma unroll
        for (int ks = 0; ks < 2; ++ks)
            qf[qs][ks] = *(const bf16x8*)(Qh + (size_t)(b*S_ + qbase + qs*16 + lo)*D_ + h*DH_ + ks*32 + g4*8);

    const f32x4 zero = {0.f, 0.f, 0.f, 0.f};

    // ---------------- loop1: rowsums only (K direct from global, barrier-free)
    float rs[2][4] = {};
    for (int kt = 0; kt < 32; ++kt) {
        const size_t kbase = (size_t)(b*S_ + kt*64)*D_ + h*DH_;
        f32x4 sacc[2][4];
        #pragma unroll
        for (int qs = 0; qs < 2; ++qs)
            #pragma unroll
            for (int ni = 0; ni < 4; ++ni) sacc[qs][ni] = zero;
        __builtin_amdgcn_s_setprio(1);
        #pragma unroll
        for (int ks = 0; ks < 2; ++ks)
            #pragma unroll
            for (int ni = 0; ni < 4; ++ni) {
                const bf16x8 kf = *(const bf16x8*)(Kh + kbase + (size_t)(ni*16 + lo)*D_ + ks*32 + g4*8);
                sacc[0][ni] = __builtin_amdgcn_mfma_f32_16x16x32_bf16(qf[0][ks], kf, sacc[0][ni], 0, 0, 0);
                sacc[1][ni] = __builtin_amdgcn_mfma_f32_16x16x32_bf16(qf[1][ks], kf, sacc[1][ni], 0, 0, 0);
            }
        __builtin_amdgcn_s_setprio(0);
        #pragma unroll
        for (int qs = 0; qs < 2; ++qs)
            #pragma unroll
            for (int ni = 0; ni < 4; ++ni)
                #pragma unroll
                for (int j = 0; j < 4; ++j)
                    rs[qs][j] += __expf(sacc[qs][ni][j] * 0.125f);
    }

    float invp[2][4];
    #pragma unroll
    for (int qs = 0; qs < 2; ++qs)
        #pragma unroll
        for (int j = 0; j < 4; ++j) {
            float r = rs[qs][j];
            r += __shfl_xor(r, 1); r += __shfl_xor(r, 2);
            r += __shfl_xor(r, 4); r += __shfl_xor(r, 8);
            invp[qs][j] = 1.0f / r;
        }

    // ---------------- loop2: r13 verbatim (staged K,V; scalar nt stores) -----
    // attn row base for this lane's rows: q = qbase + qs*16 + g4*4 + j
    float* abase = attn + ((size_t)(b*H_ + h)*S_ + qbase + g4*4)*S_;

    f32x4 cacc[2][4];
    #pragma unroll
    for (int qs = 0; qs < 2; ++qs)
        #pragma unroll
        for (int ni = 0; ni < 4; ++ni) cacc[qs][ni] = zero;

    for (int kt = 0; kt < 32; ++kt) {
        __syncthreads();   // prev readers done
        #pragma unroll
        for (int c = 0; c < 2; ++c) {
            const int sidx = c*256 + wbase + lane;
            const int row = sidx >> 3;
            const int gblk = (sidx & 7) ^ (row & 7);
            gl_lds16(Kh + (size_t)(b*S_ + kt*64 + row)*D_ + h*DH_ + gblk*8,
                     Kbuf + (size_t)(c*256 + wbase)*8);
            gl_lds16(Vt + (size_t)(b*D_ + h*DH_ + row)*S_ + kt*64 + gblk*8,
                     Vbuf + (size_t)(c*256 + wbase)*8);
        }
        __syncthreads();   // staging complete
        f32x4 sacc[2][4];
        #pragma unroll
        for (int qs = 0; qs < 2; ++qs)
            #pragma unroll
            for (int ni = 0; ni < 4; ++ni) sacc[qs][ni] = zero;
        __builtin_amdgcn_s_setprio(1);
        #pragma unroll
        for (int ks = 0; ks < 2; ++ks)
            #pragma unroll
            for (int ni = 0; ni < 4; ++ni) {
                const int row = ni*16 + lo;
                const bf16x8 kf = *(const bf16x8*)(Kbuf + row*64 + (((ks*4+g4) ^ (lo&7))*8));
                sacc[0][ni] = __builtin_amdgcn_mfma_f32_16x16x32_bf16(qf[0][ks], kf, sacc[0][ni], 0, 0, 0);
                sacc[1][ni] = __builtin_amdgcn_mfma_f32_16x16x32_bf16(qf[1][ks], kf, sacc[1][ni], 0, 0, 0);
            }
        __builtin_amdgcn_s_setprio(0);
        // exp -> P LDS (unnormalized) + scalar nt-store normalized attn
        #pragma unroll
        for (int qs = 0; qs < 2; ++qs)
            #pragma unroll
            for (int ni = 0; ni < 4; ++ni)
                #pragma unroll
                for (int j = 0; j < 4; ++j) {
                    const float p = __expf(sacc[qs][ni][j] * 0.125f);
                    const int row = qs*16 + g4*4 + j, key = ni*16 + lo;
                    Pw[row*64 + (((key >> 3) ^ (row & 7))*8) + (key & 7)] = f2b(p);
                    __builtin_nontemporal_store(p * invp[qs][j],
                        abase + ((size_t)(qs*16 + j))*S_ + kt*64 + key);
                }
        __builtin_amdgcn_s_setprio(1);
        #pragma unroll
        for (int ks = 0; ks < 2; ++ks) {
            bf16x8 vf[4];
            #pragma unroll
            for (int ni = 0; ni < 4; ++ni) {
                const int row = ni*16 + lo;
                vf[ni] = *(const bf16x8*)(Vbuf + row*64 + (((ks*4+g4) ^ (lo&7))*8));
            }
            #pragma unroll
            for (int qs = 0; qs < 2; ++qs) {
                const int prow = qs*16 + lo;
                const bf16x8 pa = *(const bf16x8*)(Pw + prow*64 + (((ks*4 + g4) ^ (lo & 7))*8));
                #pragma unroll
                for (int ni = 0; ni < 4; ++ni)
                    cacc[qs][ni] = __builtin_amdgcn_mfma_f32_16x16x32_bf16(pa, vf[ni], cacc[qs][ni], 0, 0, 0);
            }
        }
        __builtin_amdgcn_s_setprio(0);
    }

    #pragma unroll
    for (int qs = 0; qs < 2; ++qs)
        #pragma unroll
        for (int j = 0; j < 4; ++j) {
            const float inv = invp[qs][j];
            #pragma unroll
            for (int ni = 0; ni < 4; ++ni)
                ctxb[(size_t)(b*S_ + qbase + qs*16 + g4*4 + j)*D_ + h*DH_ + ni*16 + lo] =
                    f2b(cacc[qs][ni][j] * inv);
        }
}

// ---------------- output GEMM: out[M][1024] = ctx@Wo + bo (fp32 out) ---------
__global__ __launch_bounds__(256)
void gemm_out(const u16* __restrict__ Ab, const u16* __restrict__ Wt,
              const float* __restrict__ bias, float* __restrict__ Cf)
{
    const int lin = blockIdx.y*64 + blockIdx.x;
    const int cx = lin & 7, idx = lin >> 3;
    const int nx = cx*8 + (idx & 7), ny = idx >> 3;
    const int m0 = nx*128, n0 = ny*128;

    __shared__ u16 AsU[128*64];
    __shared__ u16 BsU[128*64];
    const int t = threadIdx.x;
    const int w = t >> 6, lane = t & 63;
    const int lo = lane & 15, g4 = lane >> 4;
    const int wr = w >> 1, wc = w & 1;
    const int wbase = w*64;

    const f32x4 zero = {0.f, 0.f, 0.f, 0.f};
    f32x4 acc[4][4];
    #pragma unroll
    for (int mi = 0; mi < 4; ++mi)
        #pragma unroll
        for (int ni = 0; ni < 4; ++ni) acc[mi][ni] = zero;

    for (int k0 = 0; k0 < 1024; k0 += 64) {
        __syncthreads();
        #pragma unroll
        for (int c = 0; c < 4; ++c) {
            const int sidx = c*256 + wbase + lane;
            const int row = sidx >> 3;
            const int gblk = (sidx & 7) ^ (row & 7);
            gl_lds16(Ab + (size_t)(m0+row)*D_ + k0 + gblk*8, AsU + (size_t)(c*256 + wbase)*8);
            gl_lds16(Wt + (size_t)(n0+row)*D_ + k0 + gblk*8, BsU + (size_t)(c*256 + wbase)*8);
        }
        __syncthreads();
        #pragma unroll
        for (int ks = 0; ks < 2; ++ks) {
            bf16x8 af[4], bfr[4];
            #pragma unroll
            for (int mi = 0; mi < 4; ++mi) {
                const int row = wr*64 + mi*16 + lo;
                af[mi] = *(const bf16x8*)(AsU + row*64 + (((ks*4+g4) ^ (lo&7))*8));
            }
            #pragma unroll
            for (int ni = 0; ni < 4; ++ni) {
                const int row = wc*64 + ni*16 + lo;
                bfr[ni] = *(const bf16x8*)(BsU + row*64 + (((ks*4+g4) ^ (lo&7))*8));
            }
            #pragma unroll
            for (int mi = 0; mi < 4; ++mi)
                #pragma unroll
                for (int ni = 0; ni < 4; ++ni)
                    acc[mi][ni] = __builtin_amdgcn_mfma_f32_16x16x32_bf16(
                        af[mi], bfr[ni], acc[mi][ni], 0, 0, 0);
        }
    }

    #pragma unroll
    for (int ni = 0; ni < 4; ++ni) {
        const int n = n0 + wc*64 + ni*16 + lo;
        const float bb = bias[n];
        #pragma unroll
        for (int mi = 0; mi < 4; ++mi)
            #pragma unroll
            for (int j = 0; j < 4; ++j) {
                const size_t m = (size_t)(m0 + wr*64 + mi*16 + g4*4 + j);
                Cf[m*D_ + n] = acc[mi][ni][j] + bb;
            }
    }
}

// ----------------------------------------------------------------------------
extern "C" void kernel_launch(void* const* d_in, const int* in_sizes, int n_in,
                              void* d_out, int out_size, void* d_ws, size_t ws_size,
                              hipStream_t stream)
{
    (void)in_sizes; (void)n_in; (void)out_size; (void)ws_size;
    const float* v  = (const float*)d_in[0];
    const float* k  = (const float*)d_in[1];
    const float* q  = (const float*)d_in[2];
    const float* Wq = (const float*)d_in[3];
    const float* bq = (const float*)d_in[4];
    const float* Wk = (const float*)d_in[5];
    const float* bk = (const float*)d_in[6];
    const float* Wv = (const float*)d_in[7];
    const float* bv = (const float*)d_in[8];
    const float* Wo = (const float*)d_in[9];
    const float* bo = (const float*)d_in[10];

    float* out  = (float*)d_out;                  // (B,S,D) fp32
    float* attn = out + (size_t)M_*D_;            // (B,H,S,S) fp32

    u16* qb  = (u16*)d_ws;
    u16* kb  = qb  + (size_t)M_*D_;
    u16* vb  = kb  + (size_t)M_*D_;
    u16* Wqt = vb  + (size_t)M_*D_;
    u16* Wkt = Wqt + (size_t)D_*D_;
    u16* Wvt = Wkt + (size_t)D_*D_;
    u16* Wot = Wvt + (size_t)D_*D_;
    u16* Qhb = Wot + (size_t)D_*D_;
    u16* Khb = Qhb + (size_t)M_*D_;
    u16* Vtb = Khb + (size_t)M_*D_;
    u16* ctxb = qb;                               // reuse (dead after q-proj)

    dim3 b256(256);

    cvt3       <<<dim3(4096, 3),   b256, 0, stream>>>(q, k, v, qb, kb, vb);
    wtrans4    <<<dim3(16, 16, 4), b256, 0, stream>>>(Wq, Wk, Wv, Wo, Wqt, Wkt, Wvt, Wot);
    proj_qkv   <<<dim3(64, 8, 3),  b256, 0, stream>>>(qb, kb, vb, Wqt, Wkt, Wvt,
                                                      bq, bk, bv, Qhb, Khb, Vtb);
    attn_fused5<<<dim3(16, 16, 4), b256, 0, stream>>>(Qhb, Khb, Vtb, ctxb, attn);
    gemm_out   <<<dim3(64, 8),     b256, 0, stream>>>(ctxb, Wot, bo, out);
}

// Round 16
// 469.864 us; speedup vs baseline: 1.2481x; 1.0961x over previous
//
#include <hip/hip_runtime.h>
#include <hip/hip_bf16.h>

#define B_  4
#define S_  2048
#define D_  1024
#define H_  16
#define DH_ 64
#define M_  (B_*S_)   // 8192

typedef short bf16x8 __attribute__((ext_vector_type(8)));   // 8 bf16 = 4 VGPR
typedef float f32x4  __attribute__((ext_vector_type(4)));
typedef unsigned short u16;

__device__ __forceinline__ u16 f2b(float x) {
    union { __hip_bfloat16 h; u16 u; } c; c.h = __float2bfloat16(x); return c.u;
}

// global -> LDS direct (16B per lane). LDS dst is wave-uniform base + lane*16;
// global src is per-lane (pre-swizzle applied there, rule #21/m173).
__device__ __forceinline__ void gl_lds16(const u16* g, u16* l) {
    __builtin_amdgcn_global_load_lds(
        (const __attribute__((address_space(1))) unsigned int*)g,
        (__attribute__((address_space(3))) unsigned int*)l,
        16, 0, 0);
}

// ---------------- fp32 -> bf16 bulk convert, q/k/v in one launch -------------
__global__ __launch_bounds__(256)
void cvt3(const float* __restrict__ q, const float* __restrict__ k,
          const float* __restrict__ v,
          u16* __restrict__ qb, u16* __restrict__ kb, u16* __restrict__ vb)
{
    const float* src = blockIdx.y == 0 ? q : (blockIdx.y == 1 ? k : v);
    u16*         dst = blockIdx.y == 0 ? qb : (blockIdx.y == 1 ? kb : vb);
    const int i = blockIdx.x*256 + threadIdx.x;      // 0..2^20-1 exact
    float4 a = ((const float4*)src)[2*i];
    float4 b = ((const float4*)src)[2*i+1];
    union { u16 u[8]; uint4 v4; } r;
    r.u[0]=f2b(a.x); r.u[1]=f2b(a.y); r.u[2]=f2b(a.z); r.u[3]=f2b(a.w);
    r.u[4]=f2b(b.x); r.u[5]=f2b(b.y); r.u[6]=f2b(b.z); r.u[7]=f2b(b.w);
    ((uint4*)dst)[i] = r.v4;
}

// ---------------- W[k][n] fp32 -> Wt[n][k] bf16, all four in one launch ------
__global__ __launch_bounds__(256)
void wtrans4(const float* __restrict__ Wq, const float* __restrict__ Wk,
             const float* __restrict__ Wv, const float* __restrict__ Wo,
             u16* __restrict__ Wqt, u16* __restrict__ Wkt,
             u16* __restrict__ Wvt, u16* __restrict__ Wot)
{
    const int z = blockIdx.z;
    const float* W  = z==0 ? Wq  : (z==1 ? Wk  : (z==2 ? Wv  : Wo));
    u16*         Wt = z==0 ? Wqt : (z==1 ? Wkt : (z==2 ? Wvt : Wot));
    __shared__ u16 Ts[64][80];
    const int t = threadIdx.x;
    const int k0 = blockIdx.x*64, n0 = blockIdx.y*64;
    const int kr = t >> 4, nc = (t & 15)*4;
    #pragma unroll
    for (int i = 0; i < 4; ++i) {
        const int kk = kr + i*16;
        float4 wv = *(const float4*)(W + (size_t)(k0 + kk)*D_ + n0 + nc);
        Ts[nc+0][kk] = f2b(wv.x); Ts[nc+1][kk] = f2b(wv.y);
        Ts[nc+2][kk] = f2b(wv.z); Ts[nc+3][kk] = f2b(wv.w);
    }
    __syncthreads();
    const int nr = t >> 2, kc = (t & 3)*16;
    u16* dst = Wt + (size_t)(n0 + nr)*D_ + k0 + kc;
    *(uint4*)(dst)     = *(const uint4*)(&Ts[nr][kc]);
    *(uint4*)(dst + 8) = *(const uint4*)(&Ts[nr][kc + 8]);
}

// ---------------- QKV projection GEMM, one launch (z selects) ----------------
__global__ __launch_bounds__(256)
void proj_qkv(const u16* __restrict__ qb, const u16* __restrict__ kb,
              const u16* __restrict__ vb,
              const u16* __restrict__ Wqt, const u16* __restrict__ Wkt,
              const u16* __restrict__ Wvt,
              const float* __restrict__ bq, const float* __restrict__ bk,
              const float* __restrict__ bv,
              u16* __restrict__ Qhb, u16* __restrict__ Khb,
              u16* __restrict__ Vtb)
{
    const int z = blockIdx.z;
    const u16* Ab     = z==0 ? qb  : (z==1 ? kb  : vb);
    const u16* Wt     = z==0 ? Wqt : (z==1 ? Wkt : Wvt);
    const float* bias = z==0 ? bq  : (z==1 ? bk  : bv);

    const int lin = blockIdx.y*64 + blockIdx.x;      // 0..511
    const int cx = lin & 7, idx = lin >> 3;
    const int nx = cx*8 + (idx & 7), ny = idx >> 3;  // bijective
    const int m0 = nx*128, n0 = ny*128;

    __shared__ u16 AsU[128*64];
    __shared__ u16 BsU[128*64];
    const int t = threadIdx.x;
    const int w = t >> 6, lane = t & 63;
    const int lo = lane & 15, g4 = lane >> 4;
    const int wr = w >> 1, wc = w & 1;
    const int wbase = w*64;

    const f32x4 zero = {0.f, 0.f, 0.f, 0.f};
    f32x4 acc[4][4];
    #pragma unroll
    for (int mi = 0; mi < 4; ++mi)
        #pragma unroll
        for (int ni = 0; ni < 4; ++ni) acc[mi][ni] = zero;

    for (int k0 = 0; k0 < 1024; k0 += 64) {
        __syncthreads();
        #pragma unroll
        for (int c = 0; c < 4; ++c) {
            const int sidx = c*256 + wbase + lane;
            const int row = sidx >> 3;
            const int gblk = (sidx & 7) ^ (row & 7);
            gl_lds16(Ab + (size_t)(m0+row)*D_ + k0 + gblk*8, AsU + (size_t)(c*256 + wbase)*8);
            gl_lds16(Wt + (size_t)(n0+row)*D_ + k0 + gblk*8, BsU + (size_t)(c*256 + wbase)*8);
        }
        __syncthreads();
        #pragma unroll
        for (int ks = 0; ks < 2; ++ks) {
            bf16x8 af[4], bfr[4];
            #pragma unroll
            for (int mi = 0; mi < 4; ++mi) {
                const int row = wr*64 + mi*16 + lo;
                af[mi] = *(const bf16x8*)(AsU + row*64 + (((ks*4+g4) ^ (lo&7))*8));
            }
            #pragma unroll
            for (int ni = 0; ni < 4; ++ni) {
                const int row = wc*64 + ni*16 + lo;
                bfr[ni] = *(const bf16x8*)(BsU + row*64 + (((ks*4+g4) ^ (lo&7))*8));
            }
            #pragma unroll
            for (int mi = 0; mi < 4; ++mi)
                #pragma unroll
                for (int ni = 0; ni < 4; ++ni)
                    acc[mi][ni] = __builtin_amdgcn_mfma_f32_16x16x32_bf16(
                        af[mi], bfr[ni], acc[mi][ni], 0, 0, 0);
        }
    }

    if (z < 2) {
        u16* C = z==0 ? Qhb : Khb;
        #pragma unroll
        for (int ni = 0; ni < 4; ++ni) {
            const int n = n0 + wc*64 + ni*16 + lo;
            const float bb = bias[n];
            #pragma unroll
            for (int mi = 0; mi < 4; ++mi)
                #pragma unroll
                for (int j = 0; j < 4; ++j) {
                    const size_t m = (size_t)(m0 + wr*64 + mi*16 + g4*4 + j);
                    C[m*D_ + n] = f2b(acc[mi][ni][j] + bb);
                }
        }
    } else {
        // transposed: Vt[b*D_ + n][s], s = within-batch row
        const int bb_ = m0 >> 11;
        const int sbase = (m0 & 2047) + wr*64;
        #pragma unroll
        for (int ni = 0; ni < 4; ++ni) {
            const int n = n0 + wc*64 + ni*16 + lo;
            const float bv_ = bias[n];
            u16* vrow = Vtb + (size_t)(bb_*D_ + n)*S_ + sbase;
            #pragma unroll
            for (int mi = 0; mi < 4; ++mi) {
                union { u16 u[4]; uint2 v2; } pk;
                #pragma unroll
                for (int j = 0; j < 4; ++j) pk.u[j] = f2b(acc[mi][ni][j] + bv_);
                *(uint2*)(vrow + mi*16 + g4*4) = pk.v2;  // 8B, aligned
            }
        }
    }
}

// ---------------- fused attention v6 (round 16): 2-phase prefetch ------------
// r13 structure + T3-minimum double-buffered staging (m248v2 recipe): issue
// STAGE(kt+1) into buf^1 BEFORE computing on buf, ONE barrier per kt (its
// implicit vmcnt(0) lands the prefetch). Staging latency hides under
// QK^T/exp/PV instead of sitting exposed between two barriers.
__global__ __launch_bounds__(256)
void attn_fused6(const u16* __restrict__ Qh, const u16* __restrict__ Kh,
                 const u16* __restrict__ Vt,
                 u16* __restrict__ ctxb, float* __restrict__ attn)
{
    __shared__ u16 Kbuf[2][64*64];  // 16KB double-buffered
    __shared__ u16 Vbuf[2][64*64];  // 16KB
    __shared__ u16 Plds[4*2048];    // per-wave 32q x 64key, XOR-swizzled
    const int t = threadIdx.x, w = t >> 6, lane = t & 63;
    const int lo = lane & 15, g4 = lane >> 4;
    const int wbase = w*64;

    const int lin = (blockIdx.z*16 + blockIdx.y)*16 + blockIdx.x;  // 0..1023
    const int cx = lin & 7, idx = lin >> 3;
    const int nl = cx*128 + idx;                  // bijective chunked
    const int qb_ = nl & 15, bh = nl >> 4;
    const int h = bh & 15, b = bh >> 4;
    const int qbase = qb_*128 + w*32;
    u16* Pw = Plds + w*2048;

    // per-thread staging coords (two chunks of 256 threads cover 64x64 tile)
    const int s0i = wbase + lane, s1i = 256 + wbase + lane;
    const int r0 = s0i >> 3, gb0 = (s0i & 7) ^ (r0 & 7);
    const int r1 = s1i >> 3, gb1 = (s1i & 7) ^ (r1 & 7);
    const size_t kgb0 = (size_t)(b*S_ + r0)*D_ + h*DH_ + gb0*8;   // + kt*64*D_
    const size_t kgb1 = (size_t)(b*S_ + r1)*D_ + h*DH_ + gb1*8;
    const size_t vgb0 = (size_t)(b*D_ + h*DH_ + r0)*S_ + gb0*8;   // + kt*64
    const size_t vgb1 = (size_t)(b*D_ + h*DH_ + r1)*S_ + gb1*8;
    const size_t ldst0 = (size_t)(wbase)*8, ldst1 = (size_t)(256 + wbase)*8;

    bf16x8 qf[2][2];
    #pragma unroll
    for (int qs = 0; qs < 2; ++qs)
        #pragma unroll
        for (int ks = 0; ks < 2; ++ks)
            qf[qs][ks] = *(const bf16x8*)(Qh + (size_t)(b*S_ + qbase + qs*16 + lo)*D_ + h*DH_ + ks*32 + g4*8);

    const f32x4 zero = {0.f, 0.f, 0.f, 0.f};

    // ---------------- loop1: rowsums only (K 2-phase staged) ----------------
    float rs[2][4] = {};
    // prologue: stage kt=0 into Kbuf[0]
    gl_lds16(Kh + kgb0, &Kbuf[0][0] + ldst0);
    gl_lds16(Kh + kgb1, &Kbuf[0][0] + ldst1);
    __syncthreads();
    int cur = 0;
    for (int kt = 0; kt < 32; ++kt) {
        if (kt + 1 < 32) {
            const size_t koff = (size_t)(kt+1)*64*D_;
            gl_lds16(Kh + kgb0 + koff, &Kbuf[cur^1][0] + ldst0);
            gl_lds16(Kh + kgb1 + koff, &Kbuf[cur^1][0] + ldst1);
        }
        const u16* kb_ = &Kbuf[cur][0];
        f32x4 sacc[2][4];
        #pragma unroll
        for (int qs = 0; qs < 2; ++qs)
            #pragma unroll
            for (int ni = 0; ni < 4; ++ni) sacc[qs][ni] = zero;
        __builtin_amdgcn_s_setprio(1);
        #pragma unroll
        for (int ks = 0; ks < 2; ++ks)
            #pragma unroll
            for (int ni = 0; ni < 4; ++ni) {
                const int row = ni*16 + lo;
                const bf16x8 kf = *(const bf16x8*)(kb_ + row*64 + (((ks*4+g4) ^ (lo&7))*8));
                sacc[0][ni] = __builtin_amdgcn_mfma_f32_16x16x32_bf16(qf[0][ks], kf, sacc[0][ni], 0, 0, 0);
                sacc[1][ni] = __builtin_amdgcn_mfma_f32_16x16x32_bf16(qf[1][ks], kf, sacc[1][ni], 0, 0, 0);
            }
        __builtin_amdgcn_s_setprio(0);
        #pragma unroll
        for (int qs = 0; qs < 2; ++qs)
            #pragma unroll
            for (int ni = 0; ni < 4; ++ni)
                #pragma unroll
                for (int j = 0; j < 4; ++j)
                    rs[qs][j] += __expf(sacc[qs][ni][j] * 0.125f);
        __syncthreads();   // prefetch landed + readers done
        cur ^= 1;
    }

    float invp[2][4];
    #pragma unroll
    for (int qs = 0; qs < 2; ++qs)
        #pragma unroll
        for (int j = 0; j < 4; ++j) {
            float r = rs[qs][j];
            r += __shfl_xor(r, 1); r += __shfl_xor(r, 2);
            r += __shfl_xor(r, 4); r += __shfl_xor(r, 8);
            invp[qs][j] = 1.0f / r;
        }

    // ---------------- loop2: 2-phase staged K,V + store + PV -----------------
    // attn row base for this lane's rows: q = qbase + qs*16 + g4*4 + j
    float* abase = attn + ((size_t)(b*H_ + h)*S_ + qbase + g4*4)*S_;

    f32x4 cacc[2][4];
    #pragma unroll
    for (int qs = 0; qs < 2; ++qs)
        #pragma unroll
        for (int ni = 0; ni < 4; ++ni) cacc[qs][ni] = zero;

    // prologue: stage kt=0 (loop1's last barrier guarantees buffers free)
    gl_lds16(Kh + kgb0, &Kbuf[0][0] + ldst0);
    gl_lds16(Kh + kgb1, &Kbuf[0][0] + ldst1);
    gl_lds16(Vt + vgb0, &Vbuf[0][0] + ldst0);
    gl_lds16(Vt + vgb1, &Vbuf[0][0] + ldst1);
    __syncthreads();
    cur = 0;
    for (int kt = 0; kt < 32; ++kt) {
        if (kt + 1 < 32) {
            const size_t koff = (size_t)(kt+1)*64*D_;
            const size_t voff = (size_t)(kt+1)*64;
            gl_lds16(Kh + kgb0 + koff, &Kbuf[cur^1][0] + ldst0);
            gl_lds16(Kh + kgb1 + koff, &Kbuf[cur^1][0] + ldst1);
            gl_lds16(Vt + vgb0 + voff, &Vbuf[cur^1][0] + ldst0);
            gl_lds16(Vt + vgb1 + voff, &Vbuf[cur^1][0] + ldst1);
        }
        const u16* kb_ = &Kbuf[cur][0];
        const u16* vb_ = &Vbuf[cur][0];
        f32x4 sacc[2][4];
        #pragma unroll
        for (int qs = 0; qs < 2; ++qs)
            #pragma unroll
            for (int ni = 0; ni < 4; ++ni) sacc[qs][ni] = zero;
        __builtin_amdgcn_s_setprio(1);
        #pragma unroll
        for (int ks = 0; ks < 2; ++ks)
            #pragma unroll
            for (int ni = 0; ni < 4; ++ni) {
                const int row = ni*16 + lo;
                const bf16x8 kf = *(const bf16x8*)(kb_ + row*64 + (((ks*4+g4) ^ (lo&7))*8));
                sacc[0][ni] = __builtin_amdgcn_mfma_f32_16x16x32_bf16(qf[0][ks], kf, sacc[0][ni], 0, 0, 0);
                sacc[1][ni] = __builtin_amdgcn_mfma_f32_16x16x32_bf16(qf[1][ks], kf, sacc[1][ni], 0, 0, 0);
            }
        __builtin_amdgcn_s_setprio(0);
        // exp -> P LDS (unnormalized) + scalar nt-store normalized attn
        #pragma unroll
        for (int qs = 0; qs < 2; ++qs)
            #pragma unroll
            for (int ni = 0; ni < 4; ++ni)
                #pragma unroll
                for (int j = 0; j < 4; ++j) {
                    const float p = __expf(sacc[qs][ni][j] * 0.125f);
                    const int row = qs*16 + g4*4 + j, key = ni*16 + lo;
                    Pw[row*64 + (((key >> 3) ^ (row & 7))*8) + (key & 7)] = f2b(p);
                    __builtin_nontemporal_store(p * invp[qs][j],
                        abase + ((size_t)(qs*16 + j))*S_ + kt*64 + key);
                }
        __builtin_amdgcn_s_setprio(1);
        #pragma unroll
        for (int ks = 0; ks < 2; ++ks) {
            bf16x8 vf[4];
            #pragma unroll
            for (int ni = 0; ni < 4; ++ni) {
                const int row = ni*16 + lo;
                vf[ni] = *(const bf16x8*)(vb_ + row*64 + (((ks*4+g4) ^ (lo&7))*8));
            }
            #pragma unroll
            for (int qs = 0; qs < 2; ++qs) {
                const int prow = qs*16 + lo;
                const bf16x8 pa = *(const bf16x8*)(Pw + prow*64 + (((ks*4 + g4) ^ (lo & 7))*8));
                #pragma unroll
                for (int ni = 0; ni < 4; ++ni)
                    cacc[qs][ni] = __builtin_amdgcn_mfma_f32_16x16x32_bf16(pa, vf[ni], cacc[qs][ni], 0, 0, 0);
            }
        }
        __builtin_amdgcn_s_setprio(0);
        __syncthreads();   // prefetch landed + readers done
        cur ^= 1;
    }

    #pragma unroll
    for (int qs = 0; qs < 2; ++qs)
        #pragma unroll
        for (int j = 0; j < 4; ++j) {
            const float inv = invp[qs][j];
            #pragma unroll
            for (int ni = 0; ni < 4; ++ni)
                ctxb[(size_t)(b*S_ + qbase + qs*16 + g4*4 + j)*D_ + h*DH_ + ni*16 + lo] =
                    f2b(cacc[qs][ni][j] * inv);
        }
}

// ---------------- output GEMM: out[M][1024] = ctx@Wo + bo (fp32 out) ---------
__global__ __launch_bounds__(256)
void gemm_out(const u16* __restrict__ Ab, const u16* __restrict__ Wt,
              const float* __restrict__ bias, float* __restrict__ Cf)
{
    const int lin = blockIdx.y*64 + blockIdx.x;
    const int cx = lin & 7, idx = lin >> 3;
    const int nx = cx*8 + (idx & 7), ny = idx >> 3;
    const int m0 = nx*128, n0 = ny*128;

    __shared__ u16 AsU[128*64];
    __shared__ u16 BsU[128*64];
    const int t = threadIdx.x;
    const int w = t >> 6, lane = t & 63;
    const int lo = lane & 15, g4 = lane >> 4;
    const int wr = w >> 1, wc = w & 1;
    const int wbase = w*64;

    const f32x4 zero = {0.f, 0.f, 0.f, 0.f};
    f32x4 acc[4][4];
    #pragma unroll
    for (int mi = 0; mi < 4; ++mi)
        #pragma unroll
        for (int ni = 0; ni < 4; ++ni) acc[mi][ni] = zero;

    for (int k0 = 0; k0 < 1024; k0 += 64) {
        __syncthreads();
        #pragma unroll
        for (int c = 0; c < 4; ++c) {
            const int sidx = c*256 + wbase + lane;
            const int row = sidx >> 3;
            const int gblk = (sidx & 7) ^ (row & 7);
            gl_lds16(Ab + (size_t)(m0+row)*D_ + k0 + gblk*8, AsU + (size_t)(c*256 + wbase)*8);
            gl_lds16(Wt + (size_t)(n0+row)*D_ + k0 + gblk*8, BsU + (size_t)(c*256 + wbase)*8);
        }
        __syncthreads();
        #pragma unroll
        for (int ks = 0; ks < 2; ++ks) {
            bf16x8 af[4], bfr[4];
            #pragma unroll
            for (int mi = 0; mi < 4; ++mi) {
                const int row = wr*64 + mi*16 + lo;
                af[mi] = *(const bf16x8*)(AsU + row*64 + (((ks*4+g4) ^ (lo&7))*8));
            }
            #pragma unroll
            for (int ni = 0; ni < 4; ++ni) {
                const int row = wc*64 + ni*16 + lo;
                bfr[ni] = *(const bf16x8*)(BsU + row*64 + (((ks*4+g4) ^ (lo&7))*8));
            }
            #pragma unroll
            for (int mi = 0; mi < 4; ++mi)
                #pragma unroll
                for (int ni = 0; ni < 4; ++ni)
                    acc[mi][ni] = __builtin_amdgcn_mfma_f32_16x16x32_bf16(
                        af[mi], bfr[ni], acc[mi][ni], 0, 0, 0);
        }
    }

    #pragma unroll
    for (int ni = 0; ni < 4; ++ni) {
        const int n = n0 + wc*64 + ni*16 + lo;
        const float bb = bias[n];
        #pragma unroll
        for (int mi = 0; mi < 4; ++mi)
            #pragma unroll
            for (int j = 0; j < 4; ++j) {
                const size_t m = (size_t)(m0 + wr*64 + mi*16 + g4*4 + j);
                Cf[m*D_ + n] = acc[mi][ni][j] + bb;
            }
    }
}

// ----------------------------------------------------------------------------
extern "C" void kernel_launch(void* const* d_in, const int* in_sizes, int n_in,
                              void* d_out, int out_size, void* d_ws, size_t ws_size,
                              hipStream_t stream)
{
    (void)in_sizes; (void)n_in; (void)out_size; (void)ws_size;
    const float* v  = (const float*)d_in[0];
    const float* k  = (const float*)d_in[1];
    const float* q  = (const float*)d_in[2];
    const float* Wq = (const float*)d_in[3];
    const float* bq = (const float*)d_in[4];
    const float* Wk = (const float*)d_in[5];
    const float* bk = (const float*)d_in[6];
    const float* Wv = (const float*)d_in[7];
    const float* bv = (const float*)d_in[8];
    const float* Wo = (const float*)d_in[9];
    const float* bo = (const float*)d_in[10];

    float* out  = (float*)d_out;                  // (B,S,D) fp32
    float* attn = out + (size_t)M_*D_;            // (B,H,S,S) fp32

    u16* qb  = (u16*)d_ws;
    u16* kb  = qb  + (size_t)M_*D_;
    u16* vb  = kb  + (size_t)M_*D_;
    u16* Wqt = vb  + (size_t)M_*D_;
    u16* Wkt = Wqt + (size_t)D_*D_;
    u16* Wvt = Wkt + (size_t)D_*D_;
    u16* Wot = Wvt + (size_t)D_*D_;
    u16* Qhb = Wot + (size_t)D_*D_;
    u16* Khb = Qhb + (size_t)M_*D_;
    u16* Vtb = Khb + (size_t)M_*D_;
    u16* ctxb = qb;                               // reuse (dead after q-proj)

    dim3 b256(256);

    cvt3       <<<dim3(4096, 3),   b256, 0, stream>>>(q, k, v, qb, kb, vb);
    wtrans4    <<<dim3(16, 16, 4), b256, 0, stream>>>(Wq, Wk, Wv, Wo, Wqt, Wkt, Wvt, Wot);
    proj_qkv   <<<dim3(64, 8, 3),  b256, 0, stream>>>(qb, kb, vb, Wqt, Wkt, Wvt,
                                                      bq, bk, bv, Qhb, Khb, Vtb);
    attn_fused6<<<dim3(16, 16, 4), b256, 0, stream>>>(Qhb, Khb, Vtb, ctxb, attn);
    gemm_out   <<<dim3(64, 8),     b256, 0, stream>>>(ctxb, Wot, bo, out);
}

// Round 17
// 467.404 us; speedup vs baseline: 1.2546x; 1.0053x over previous
//
#include <hip/hip_runtime.h>
#include <hip/hip_bf16.h>

#define B_  4
#define S_  2048
#define D_  1024
#define H_  16
#define DH_ 64
#define M_  (B_*S_)   // 8192

typedef short bf16x8 __attribute__((ext_vector_type(8)));   // 8 bf16 = 4 VGPR
typedef float f32x4  __attribute__((ext_vector_type(4)));
typedef unsigned short u16;

__device__ __forceinline__ u16 f2b(float x) {
    union { __hip_bfloat16 h; u16 u; } c; c.h = __float2bfloat16(x); return c.u;
}

// global -> LDS direct (16B per lane). LDS dst is wave-uniform base + lane*16;
// global src is per-lane (pre-swizzle applied there, rule #21/m173).
__device__ __forceinline__ void gl_lds16(const u16* g, u16* l) {
    __builtin_amdgcn_global_load_lds(
        (const __attribute__((address_space(1))) unsigned int*)g,
        (__attribute__((address_space(3))) unsigned int*)l,
        16, 0, 0);
}

// ---------------- fp32 -> bf16 bulk convert, q/k/v in one launch -------------
__global__ __launch_bounds__(256)
void cvt3(const float* __restrict__ q, const float* __restrict__ k,
          const float* __restrict__ v,
          u16* __restrict__ qb, u16* __restrict__ kb, u16* __restrict__ vb)
{
    const float* src = blockIdx.y == 0 ? q : (blockIdx.y == 1 ? k : v);
    u16*         dst = blockIdx.y == 0 ? qb : (blockIdx.y == 1 ? kb : vb);
    const int i = blockIdx.x*256 + threadIdx.x;      // 0..2^20-1 exact
    float4 a = ((const float4*)src)[2*i];
    float4 b = ((const float4*)src)[2*i+1];
    union { u16 u[8]; uint4 v4; } r;
    r.u[0]=f2b(a.x); r.u[1]=f2b(a.y); r.u[2]=f2b(a.z); r.u[3]=f2b(a.w);
    r.u[4]=f2b(b.x); r.u[5]=f2b(b.y); r.u[6]=f2b(b.z); r.u[7]=f2b(b.w);
    ((uint4*)dst)[i] = r.v4;
}

// ---------------- W[k][n] fp32 -> Wt[n][k] bf16, all four in one launch ------
__global__ __launch_bounds__(256)
void wtrans4(const float* __restrict__ Wq, const float* __restrict__ Wk,
             const float* __restrict__ Wv, const float* __restrict__ Wo,
             u16* __restrict__ Wqt, u16* __restrict__ Wkt,
             u16* __restrict__ Wvt, u16* __restrict__ Wot)
{
    const int z = blockIdx.z;
    const float* W  = z==0 ? Wq  : (z==1 ? Wk  : (z==2 ? Wv  : Wo));
    u16*         Wt = z==0 ? Wqt : (z==1 ? Wkt : (z==2 ? Wvt : Wot));
    __shared__ u16 Ts[64][80];
    const int t = threadIdx.x;
    const int k0 = blockIdx.x*64, n0 = blockIdx.y*64;
    const int kr = t >> 4, nc = (t & 15)*4;
    #pragma unroll
    for (int i = 0; i < 4; ++i) {
        const int kk = kr + i*16;
        float4 wv = *(const float4*)(W + (size_t)(k0 + kk)*D_ + n0 + nc);
        Ts[nc+0][kk] = f2b(wv.x); Ts[nc+1][kk] = f2b(wv.y);
        Ts[nc+2][kk] = f2b(wv.z); Ts[nc+3][kk] = f2b(wv.w);
    }
    __syncthreads();
    const int nr = t >> 2, kc = (t & 3)*16;
    u16* dst = Wt + (size_t)(n0 + nr)*D_ + k0 + kc;
    *(uint4*)(dst)     = *(const uint4*)(&Ts[nr][kc]);
    *(uint4*)(dst + 8) = *(const uint4*)(&Ts[nr][kc + 8]);
}

// ---------------- QKV projection GEMM, one launch (z selects) ----------------
__global__ __launch_bounds__(256)
void proj_qkv(const u16* __restrict__ qb, const u16* __restrict__ kb,
              const u16* __restrict__ vb,
              const u16* __restrict__ Wqt, const u16* __restrict__ Wkt,
              const u16* __restrict__ Wvt,
              const float* __restrict__ bq, const float* __restrict__ bk,
              const float* __restrict__ bv,
              u16* __restrict__ Qhb, u16* __restrict__ Khb,
              u16* __restrict__ Vtb)
{
    const int z = blockIdx.z;
    const u16* Ab     = z==0 ? qb  : (z==1 ? kb  : vb);
    const u16* Wt     = z==0 ? Wqt : (z==1 ? Wkt : Wvt);
    const float* bias = z==0 ? bq  : (z==1 ? bk  : bv);

    const int lin = blockIdx.y*64 + blockIdx.x;      // 0..511
    const int cx = lin & 7, idx = lin >> 3;
    const int nx = cx*8 + (idx & 7), ny = idx >> 3;  // bijective
    const int m0 = nx*128, n0 = ny*128;

    __shared__ u16 AsU[128*64];
    __shared__ u16 BsU[128*64];
    const int t = threadIdx.x;
    const int w = t >> 6, lane = t & 63;
    const int lo = lane & 15, g4 = lane >> 4;
    const int wr = w >> 1, wc = w & 1;
    const int wbase = w*64;

    const f32x4 zero = {0.f, 0.f, 0.f, 0.f};
    f32x4 acc[4][4];
    #pragma unroll
    for (int mi = 0; mi < 4; ++mi)
        #pragma unroll
        for (int ni = 0; ni < 4; ++ni) acc[mi][ni] = zero;

    for (int k0 = 0; k0 < 1024; k0 += 64) {
        __syncthreads();
        #pragma unroll
        for (int c = 0; c < 4; ++c) {
            const int sidx = c*256 + wbase + lane;
            const int row = sidx >> 3;
            const int gblk = (sidx & 7) ^ (row & 7);
            gl_lds16(Ab + (size_t)(m0+row)*D_ + k0 + gblk*8, AsU + (size_t)(c*256 + wbase)*8);
            gl_lds16(Wt + (size_t)(n0+row)*D_ + k0 + gblk*8, BsU + (size_t)(c*256 + wbase)*8);
        }
        __syncthreads();
        #pragma unroll
        for (int ks = 0; ks < 2; ++ks) {
            bf16x8 af[4], bfr[4];
            #pragma unroll
            for (int mi = 0; mi < 4; ++mi) {
                const int row = wr*64 + mi*16 + lo;
                af[mi] = *(const bf16x8*)(AsU + row*64 + (((ks*4+g4) ^ (lo&7))*8));
            }
            #pragma unroll
            for (int ni = 0; ni < 4; ++ni) {
                const int row = wc*64 + ni*16 + lo;
                bfr[ni] = *(const bf16x8*)(BsU + row*64 + (((ks*4+g4) ^ (lo&7))*8));
            }
            #pragma unroll
            for (int mi = 0; mi < 4; ++mi)
                #pragma unroll
                for (int ni = 0; ni < 4; ++ni)
                    acc[mi][ni] = __builtin_amdgcn_mfma_f32_16x16x32_bf16(
                        af[mi], bfr[ni], acc[mi][ni], 0, 0, 0);
        }
    }

    if (z < 2) {
        u16* C = z==0 ? Qhb : Khb;
        #pragma unroll
        for (int ni = 0; ni < 4; ++ni) {
            const int n = n0 + wc*64 + ni*16 + lo;
            const float bb = bias[n];
            #pragma unroll
            for (int mi = 0; mi < 4; ++mi)
                #pragma unroll
                for (int j = 0; j < 4; ++j) {
                    const size_t m = (size_t)(m0 + wr*64 + mi*16 + g4*4 + j);
                    C[m*D_ + n] = f2b(acc[mi][ni][j] + bb);
                }
        }
    } else {
        // transposed: Vt[b*D_ + n][s], s = within-batch row
        const int bb_ = m0 >> 11;
        const int sbase = (m0 & 2047) + wr*64;
        #pragma unroll
        for (int ni = 0; ni < 4; ++ni) {
            const int n = n0 + wc*64 + ni*16 + lo;
            const float bv_ = bias[n];
            u16* vrow = Vtb + (size_t)(bb_*D_ + n)*S_ + sbase;
            #pragma unroll
            for (int mi = 0; mi < 4; ++mi) {
                union { u16 u[4]; uint2 v2; } pk;
                #pragma unroll
                for (int j = 0; j < 4; ++j) pk.u[j] = f2b(acc[mi][ni][j] + bv_);
                *(uint2*)(vrow + mi*16 + g4*4) = pk.v2;  // 8B, aligned
            }
        }
    }
}

// ---------------- fused attention v7 (round 17): 128-key tiles ---------------
// r13 structure with the staging tile doubled to 128 keys -> 16 iterations
// per loop, HALVING barrier count (each __syncthreads drains vmcnt(0)
// including in-flight nt-stores; fewer global drain points). P/PV sub-steps
// stay 64-wide (2 subs per tile, barrier-free: Plds is per-wave).
// LDS: Kbuf 16K [128k][64d] + Vbuf 16K [64d][128k] + Plds 16K = 48KB.
__global__ __launch_bounds__(256)
void attn_fused7(const u16* __restrict__ Qh, const u16* __restrict__ Kh,
                 const u16* __restrict__ Vt,
                 u16* __restrict__ ctxb, float* __restrict__ attn)
{
    __shared__ u16 Kbuf[128*64];    // [key][d], chunk-swizzled
    __shared__ u16 Vbuf[64*128];    // [d][key], chunk-swizzled
    __shared__ u16 Plds[4*2048];    // per-wave 32q x 64key, XOR-swizzled
    const int t = threadIdx.x, w = t >> 6, lane = t & 63;
    const int lo = lane & 15, g4 = lane >> 4;
    const int wbase = w*64;

    const int lin = (blockIdx.z*16 + blockIdx.y)*16 + blockIdx.x;  // 0..1023
    const int cx = lin & 7, idx = lin >> 3;
    const int nl = cx*128 + idx;                  // bijective chunked
    const int qb_ = nl & 15, bh = nl >> 4;
    const int h = bh & 15, b = bh >> 4;
    const int qbase = qb_*128 + w*32;
    u16* Pw = Plds + w*2048;

    bf16x8 qf[2][2];
    #pragma unroll
    for (int qs = 0; qs < 2; ++qs)
        #pragma unroll
        for (int ks = 0; ks < 2; ++ks)
            qf[qs][ks] = *(const bf16x8*)(Qh + (size_t)(b*S_ + qbase + qs*16 + lo)*D_ + h*DH_ + ks*32 + g4*8);

    const f32x4 zero = {0.f, 0.f, 0.f, 0.f};

    // ---------------- loop1: rowsums only (K via LDS, 128-key tiles) ---------
    float rs[2][4] = {};
    for (int kt2 = 0; kt2 < 16; ++kt2) {
        __syncthreads();   // prev readers done
        #pragma unroll
        for (int c = 0; c < 4; ++c) {
            const int sidx = c*256 + wbase + lane;       // 0..1023
            const int row = sidx >> 3;                   // 0..127 (key)
            const int gblk = (sidx & 7) ^ (row & 7);
            gl_lds16(Kh + (size_t)(b*S_ + kt2*128 + row)*D_ + h*DH_ + gblk*8,
                     Kbuf + (size_t)(c*256 + wbase)*8);
        }
        __syncthreads();   // staging complete
        #pragma unroll
        for (int sub = 0; sub < 2; ++sub) {
            f32x4 sacc[2][4];
            #pragma unroll
            for (int qs = 0; qs < 2; ++qs)
                #pragma unroll
                for (int ni = 0; ni < 4; ++ni) sacc[qs][ni] = zero;
            __builtin_amdgcn_s_setprio(1);
            #pragma unroll
            for (int ks = 0; ks < 2; ++ks)
                #pragma unroll
                for (int ni = 0; ni < 4; ++ni) {
                    const int row = sub*64 + ni*16 + lo;
                    const bf16x8 kf = *(const bf16x8*)(Kbuf + row*64 + (((ks*4+g4) ^ (lo&7))*8));
                    sacc[0][ni] = __builtin_amdgcn_mfma_f32_16x16x32_bf16(qf[0][ks], kf, sacc[0][ni], 0, 0, 0);
                    sacc[1][ni] = __builtin_amdgcn_mfma_f32_16x16x32_bf16(qf[1][ks], kf, sacc[1][ni], 0, 0, 0);
                }
            __builtin_amdgcn_s_setprio(0);
            #pragma unroll
            for (int qs = 0; qs < 2; ++qs)
                #pragma unroll
                for (int ni = 0; ni < 4; ++ni)
                    #pragma unroll
                    for (int j = 0; j < 4; ++j)
                        rs[qs][j] += __expf(sacc[qs][ni][j] * 0.125f);
        }
    }

    float invp[2][4];
    #pragma unroll
    for (int qs = 0; qs < 2; ++qs)
        #pragma unroll
        for (int j = 0; j < 4; ++j) {
            float r = rs[qs][j];
            r += __shfl_xor(r, 1); r += __shfl_xor(r, 2);
            r += __shfl_xor(r, 4); r += __shfl_xor(r, 8);
            invp[qs][j] = 1.0f / r;
        }

    // ---------------- loop2: 128-key tiles, K+V staged, store + PV -----------
    // attn row base for this lane's rows: q = qbase + qs*16 + g4*4 + j
    float* abase = attn + ((size_t)(b*H_ + h)*S_ + qbase + g4*4)*S_;

    f32x4 cacc[2][4];
    #pragma unroll
    for (int qs = 0; qs < 2; ++qs)
        #pragma unroll
        for (int ni = 0; ni < 4; ++ni) cacc[qs][ni] = zero;

    for (int kt2 = 0; kt2 < 16; ++kt2) {
        __syncthreads();   // prev readers done
        #pragma unroll
        for (int c = 0; c < 4; ++c) {
            const int sidx = c*256 + wbase + lane;
            // K tile: [128 keys][64 d], 8 chunks/row
            const int krow = sidx >> 3;
            const int kgb = (sidx & 7) ^ (krow & 7);
            gl_lds16(Kh + (size_t)(b*S_ + kt2*128 + krow)*D_ + h*DH_ + kgb*8,
                     Kbuf + (size_t)(c*256 + wbase)*8);
            // V tile: [64 d][128 keys], 16 chunks/row
            const int vrow = sidx >> 4;
            const int vgb = (sidx & 15) ^ (vrow & 7);
            gl_lds16(Vt + (size_t)(b*D_ + h*DH_ + vrow)*S_ + kt2*128 + vgb*8,
                     Vbuf + (size_t)(c*256 + wbase)*8);
        }
        __syncthreads();   // staging complete
        #pragma unroll
        for (int sub = 0; sub < 2; ++sub) {
            const int kcol0 = kt2*128 + sub*64;
            f32x4 sacc[2][4];
            #pragma unroll
            for (int qs = 0; qs < 2; ++qs)
                #pragma unroll
                for (int ni = 0; ni < 4; ++ni) sacc[qs][ni] = zero;
            __builtin_amdgcn_s_setprio(1);
            #pragma unroll
            for (int ks = 0; ks < 2; ++ks)
                #pragma unroll
                for (int ni = 0; ni < 4; ++ni) {
                    const int row = sub*64 + ni*16 + lo;
                    const bf16x8 kf = *(const bf16x8*)(Kbuf + row*64 + (((ks*4+g4) ^ (lo&7))*8));
                    sacc[0][ni] = __builtin_amdgcn_mfma_f32_16x16x32_bf16(qf[0][ks], kf, sacc[0][ni], 0, 0, 0);
                    sacc[1][ni] = __builtin_amdgcn_mfma_f32_16x16x32_bf16(qf[1][ks], kf, sacc[1][ni], 0, 0, 0);
                }
            __builtin_amdgcn_s_setprio(0);
            // exp -> P LDS (unnormalized) + scalar nt-store normalized attn
            #pragma unroll
            for (int qs = 0; qs < 2; ++qs)
                #pragma unroll
                for (int ni = 0; ni < 4; ++ni)
                    #pragma unroll
                    for (int j = 0; j < 4; ++j) {
                        const float p = __expf(sacc[qs][ni][j] * 0.125f);
                        const int row = qs*16 + g4*4 + j, key = ni*16 + lo;
                        Pw[row*64 + (((key >> 3) ^ (row & 7))*8) + (key & 7)] = f2b(p);
                        __builtin_nontemporal_store(p * invp[qs][j],
                            abase + ((size_t)(qs*16 + j))*S_ + kcol0 + key);
                    }
            __builtin_amdgcn_s_setprio(1);
            #pragma unroll
            for (int ks = 0; ks < 2; ++ks) {
                bf16x8 vf[4];
                #pragma unroll
                for (int ni = 0; ni < 4; ++ni) {
                    const int row = ni*16 + lo;          // d-row 0..63
                    const int c16 = sub*8 + ks*4 + g4;   // key-chunk 0..15
                    vf[ni] = *(const bf16x8*)(Vbuf + row*128 + ((c16 ^ (lo&7))*8));
                }
                #pragma unroll
                for (int qs = 0; qs < 2; ++qs) {
                    const int prow = qs*16 + lo;
                    const bf16x8 pa = *(const bf16x8*)(Pw + prow*64 + (((ks*4 + g4) ^ (lo & 7))*8));
                    #pragma unroll
                    for (int ni = 0; ni < 4; ++ni)
                        cacc[qs][ni] = __builtin_amdgcn_mfma_f32_16x16x32_bf16(pa, vf[ni], cacc[qs][ni], 0, 0, 0);
                }
            }
            __builtin_amdgcn_s_setprio(0);
        }
    }

    #pragma unroll
    for (int qs = 0; qs < 2; ++qs)
        #pragma unroll
        for (int j = 0; j < 4; ++j) {
            const float inv = invp[qs][j];
            #pragma unroll
            for (int ni = 0; ni < 4; ++ni)
                ctxb[(size_t)(b*S_ + qbase + qs*16 + g4*4 + j)*D_ + h*DH_ + ni*16 + lo] =
                    f2b(cacc[qs][ni][j] * inv);
        }
}

// ---------------- output GEMM: out[M][1024] = ctx@Wo + bo (fp32 out) ---------
__global__ __launch_bounds__(256)
void gemm_out(const u16* __restrict__ Ab, const u16* __restrict__ Wt,
              const float* __restrict__ bias, float* __restrict__ Cf)
{
    const int lin = blockIdx.y*64 + blockIdx.x;
    const int cx = lin & 7, idx = lin >> 3;
    const int nx = cx*8 + (idx & 7), ny = idx >> 3;
    const int m0 = nx*128, n0 = ny*128;

    __shared__ u16 AsU[128*64];
    __shared__ u16 BsU[128*64];
    const int t = threadIdx.x;
    const int w = t >> 6, lane = t & 63;
    const int lo = lane & 15, g4 = lane >> 4;
    const int wr = w >> 1, wc = w & 1;
    const int wbase = w*64;

    const f32x4 zero = {0.f, 0.f, 0.f, 0.f};
    f32x4 acc[4][4];
    #pragma unroll
    for (int mi = 0; mi < 4; ++mi)
        #pragma unroll
        for (int ni = 0; ni < 4; ++ni) acc[mi][ni] = zero;

    for (int k0 = 0; k0 < 1024; k0 += 64) {
        __syncthreads();
        #pragma unroll
        for (int c = 0; c < 4; ++c) {
            const int sidx = c*256 + wbase + lane;
            const int row = sidx >> 3;
            const int gblk = (sidx & 7) ^ (row & 7);
            gl_lds16(Ab + (size_t)(m0+row)*D_ + k0 + gblk*8, AsU + (size_t)(c*256 + wbase)*8);
            gl_lds16(Wt + (size_t)(n0+row)*D_ + k0 + gblk*8, BsU + (size_t)(c*256 + wbase)*8);
        }
        __syncthreads();
        #pragma unroll
        for (int ks = 0; ks < 2; ++ks) {
            bf16x8 af[4], bfr[4];
            #pragma unroll
            for (int mi = 0; mi < 4; ++mi) {
                const int row = wr*64 + mi*16 + lo;
                af[mi] = *(const bf16x8*)(AsU + row*64 + (((ks*4+g4) ^ (lo&7))*8));
            }
            #pragma unroll
            for (int ni = 0; ni < 4; ++ni) {
                const int row = wc*64 + ni*16 + lo;
                bfr[ni] = *(const bf16x8*)(BsU + row*64 + (((ks*4+g4) ^ (lo&7))*8));
            }
            #pragma unroll
            for (int mi = 0; mi < 4; ++mi)
                #pragma unroll
                for (int ni = 0; ni < 4; ++ni)
                    acc[mi][ni] = __builtin_amdgcn_mfma_f32_16x16x32_bf16(
                        af[mi], bfr[ni], acc[mi][ni], 0, 0, 0);
        }
    }

    #pragma unroll
    for (int ni = 0; ni < 4; ++ni) {
        const int n = n0 + wc*64 + ni*16 + lo;
        const float bb = bias[n];
        #pragma unroll
        for (int mi = 0; mi < 4; ++mi)
            #pragma unroll
            for (int j = 0; j < 4; ++j) {
                const size_t m = (size_t)(m0 + wr*64 + mi*16 + g4*4 + j);
                Cf[m*D_ + n] = acc[mi][ni][j] + bb;
            }
    }
}

// ----------------------------------------------------------------------------
extern "C" void kernel_launch(void* const* d_in, const int* in_sizes, int n_in,
                              void* d_out, int out_size, void* d_ws, size_t ws_size,
                              hipStream_t stream)
{
    (void)in_sizes; (void)n_in; (void)out_size; (void)ws_size;
    const float* v  = (const float*)d_in[0];
    const float* k  = (const float*)d_in[1];
    const float* q  = (const float*)d_in[2];
    const float* Wq = (const float*)d_in[3];
    const float* bq = (const float*)d_in[4];
    const float* Wk = (const float*)d_in[5];
    const float* bk = (const float*)d_in[6];
    const float* Wv = (const float*)d_in[7];
    const float* bv = (const float*)d_in[8];
    const float* Wo = (const float*)d_in[9];
    const float* bo = (const float*)d_in[10];

    float* out  = (float*)d_out;                  // (B,S,D) fp32
    float* attn = out + (size_t)M_*D_;            // (B,H,S,S) fp32

    u16* qb  = (u16*)d_ws;
    u16* kb  = qb  + (size_t)M_*D_;
    u16* vb  = kb  + (size_t)M_*D_;
    u16* Wqt = vb  + (size_t)M_*D_;
    u16* Wkt = Wqt + (size_t)D_*D_;
    u16* Wvt = Wkt + (size_t)D_*D_;
    u16* Wot = Wvt + (size_t)D_*D_;
    u16* Qhb = Wot + (size_t)D_*D_;
    u16* Khb = Qhb + (size_t)M_*D_;
    u16* Vtb = Khb + (size_t)M_*D_;
    u16* ctxb = qb;                               // reuse (dead after q-proj)

    dim3 b256(256);

    cvt3       <<<dim3(4096, 3),   b256, 0, stream>>>(q, k, v, qb, kb, vb);
    wtrans4    <<<dim3(16, 16, 4), b256, 0, stream>>>(Wq, Wk, Wv, Wo, Wqt, Wkt, Wvt, Wot);
    proj_qkv   <<<dim3(64, 8, 3),  b256, 0, stream>>>(qb, kb, vb, Wqt, Wkt, Wvt,
                                                      bq, bk, bv, Qhb, Khb, Vtb);
    attn_fused7<<<dim3(16, 16, 4), b256, 0, stream>>>(Qhb, Khb, Vtb, ctxb, attn);
    gemm_out   <<<dim3(64, 8),     b256, 0, stream>>>(ctxb, Wot, bo, out);
}